// Round 1
// baseline (379.716 us; speedup 1.0000x reference)
//
#include <hip/hip_runtime.h>

typedef unsigned short u16;
typedef __attribute__((ext_vector_type(8))) short bvec8;   // 8 x bf16 (4 VGPR)
typedef __attribute__((ext_vector_type(4))) float fvec4;   // MFMA 16x16 accumulator

__device__ __forceinline__ u16 f2bf(float f) {
  unsigned int b = __float_as_uint(f);
  b += 0x7FFFu + ((b >> 16) & 1u);          // round-to-nearest-even
  return (u16)(b >> 16);
}

// async global->LDS, 16B per lane. LDS dest = wave-uniform base + lane*16.
__device__ __forceinline__ void gl_lds16(const void* g, void* l) {
  __builtin_amdgcn_global_load_lds(
      (__attribute__((address_space(1))) const unsigned int*)g,
      (__attribute__((address_space(3))) unsigned int*)l, 16, 0, 0);
}

// ---------------------------------------------------------------------------
// f32 -> bf16 elementwise convert (vectorized x4)
// ---------------------------------------------------------------------------
__global__ __launch_bounds__(256) void cvt_bf16(const float* __restrict__ in,
                                                u16* __restrict__ out, int n4) {
  int i = blockIdx.x * 256 + threadIdx.x;
  if (i < n4) {
    float4 v = ((const float4*)in)[i];
    ushort4 o;
    o.x = f2bf(v.x); o.y = f2bf(v.y); o.z = f2bf(v.z); o.w = f2bf(v.w);
    ((ushort4*)out)[i] = o;
  }
}

// ---------------------------------------------------------------------------
// C[M=8192, N=1024] = A[8192,1024] @ W[1024,1024]^T   (both K-contiguous bf16)
// 128x128 tile, BK=32, 4 waves each computing 64x64 (4x4 of 16x16x32 MFMA).
// MODE 0: bf16 out, [B,H,S,64] layout (Q/K), scaled.  MODE 2: bf16 out,
// [B,H,64,S] (V transposed).  MODE 3: f32 out, row-major [n][e] (final).
// XOR-swizzle on 8-elem blocks breaks ds_read_b128 bank aliasing; swizzle is
// applied on the GLOBAL source address so global_load_lds's forced
// base+lane*16 LDS layout still works.
// ---------------------------------------------------------------------------
template<int MODE>
__global__ __launch_bounds__(256, 2) void gemm_bt(const u16* __restrict__ A,
                                                  const u16* __restrict__ W,
                                                  void* __restrict__ Cout,
                                                  float scale) {
  __shared__ u16 As[128 * 32];
  __shared__ u16 Bs[128 * 32];
  const int tid = threadIdx.x;
  const int w = tid >> 6, lane = tid & 63;
  const int lanelo = lane & 15, quad = lane >> 4;
  const int m0 = blockIdx.x * 128, n0 = blockIdx.y * 128;
  const int wm = (w & 1) * 64, wn = (w >> 1) * 64;

  fvec4 acc[4][4] = {};

  // LDS fragment read offsets (constant over K loop)
  int aoff[4], boff[4];
#pragma unroll
  for (int i = 0; i < 4; ++i) {
    int ra = wm + i * 16 + lanelo;
    int sA = (ra ^ (ra >> 2)) & 3;
    aoff[i] = ra * 32 + ((quad ^ sA) << 3);
    int rb = wn + i * 16 + lanelo;
    int sB = (rb ^ (rb >> 2)) & 3;
    boff[i] = rb * 32 + ((quad ^ sB) << 3);
  }
  // staging addresses (swizzled source block per LDS slot)
  const u16* gA[2]; const u16* gB[2]; int ldso[2];
#pragma unroll
  for (int t = 0; t < 2; ++t) {
    int idx = (w * 2 + t) * 64 + lane;          // 16B-chunk id within tile
    int row = idx >> 2, bs = idx & 3;
    int s = (row ^ (row >> 2)) & 3;
    gA[t] = A + (m0 + row) * 1024 + ((bs ^ s) << 3);
    gB[t] = W + (n0 + row) * 1024 + ((bs ^ s) << 3);
    ldso[t] = (w * 2 + t) * 512;
  }

  for (int k0 = 0; k0 < 1024; k0 += 32) {
    __syncthreads();
#pragma unroll
    for (int t = 0; t < 2; ++t) {
      gl_lds16(gA[t] + k0, &As[ldso[t]]);
      gl_lds16(gB[t] + k0, &Bs[ldso[t]]);
    }
    __syncthreads();
    bvec8 a[4], b[4];
#pragma unroll
    for (int i = 0; i < 4; ++i) a[i] = *(const bvec8*)&As[aoff[i]];
#pragma unroll
    for (int j = 0; j < 4; ++j) b[j] = *(const bvec8*)&Bs[boff[j]];
#pragma unroll
    for (int i = 0; i < 4; ++i)
#pragma unroll
      for (int j = 0; j < 4; ++j)
        acc[i][j] = __builtin_amdgcn_mfma_f32_16x16x32_bf16(a[i], b[j], acc[i][j], 0, 0, 0);
  }

  // epilogue: C row m = quad*4+r, col n = lanelo (verified m89/m91 layout)
  if (MODE == 3) {
    float* C = (float*)Cout;
#pragma unroll
    for (int i = 0; i < 4; ++i) {
      const int mg = m0 + wm + i * 16 + quad * 4;
#pragma unroll
      for (int j = 0; j < 4; ++j) {
        const int ng = n0 + wn + j * 16 + lanelo;
#pragma unroll
        for (int r = 0; r < 4; ++r) C[(mg + r) * 1024 + ng] = acc[i][j][r];
      }
    }
  } else if (MODE == 2) {
    u16* C = (u16*)Cout;
#pragma unroll
    for (int i = 0; i < 4; ++i) {
      const int mg = m0 + wm + i * 16 + quad * 4;    // multiple of 4
      const int bidx = mg >> 11, srow = mg & 2047;
#pragma unroll
      for (int j = 0; j < 4; ++j) {
        const int ng = n0 + wn + j * 16 + lanelo;
        const int hh = ng >> 6, dd = ng & 63;
        ushort4 pk;
        pk.x = f2bf(acc[i][j][0]); pk.y = f2bf(acc[i][j][1]);
        pk.z = f2bf(acc[i][j][2]); pk.w = f2bf(acc[i][j][3]);
        *(ushort4*)&C[(bidx * 16 + hh) * 131072 + dd * 2048 + srow] = pk;
      }
    }
  } else {
    u16* C = (u16*)Cout;
#pragma unroll
    for (int i = 0; i < 4; ++i) {
      const int mg0 = m0 + wm + i * 16 + quad * 4;
#pragma unroll
      for (int j = 0; j < 4; ++j) {
        const int ng = n0 + wn + j * 16 + lanelo;
        const int hh = ng >> 6, dd = ng & 63;
#pragma unroll
        for (int r = 0; r < 4; ++r) {
          const int mg = mg0 + r;
          C[((mg >> 11) * 16 + hh) * 131072 + (mg & 2047) * 64 + dd] =
              f2bf(acc[i][j][r] * scale);
        }
      }
    }
  }
}

// ---------------------------------------------------------------------------
// Flash attention: one block = 128 Q rows of one (b,h); 4 waves x 32 rows.
// Q pre-scaled by 1/8 at projection. K [B,H,S,64]; V stored [B,H,64,S] so it
// is directly the PV B-operand. Online softmax fully in-register (row stats
// live in the 16-lane group owning the row). P goes through per-wave LDS to
// convert MFMA C-layout -> A-layout (m120-verified transform).
// ---------------------------------------------------------------------------
__global__ __launch_bounds__(256, 2) void attn(const u16* __restrict__ Qb,
                                               const u16* __restrict__ Kb,
                                               const u16* __restrict__ Vt,
                                               u16* __restrict__ Ob) {
  __shared__ u16 Ks[128 * 64];
  __shared__ u16 Vs[64 * 128];
  __shared__ u16 Ps[4][32 * 128];
  const int tid = threadIdx.x;
  const int w = tid >> 6, lane = tid & 63;
  const int lanelo = lane & 15, quad = lane >> 4;
  const int bh = blockIdx.y;
  const int sq0 = blockIdx.x * 128 + w * 32;
  const u16* Qh = Qb + bh * 131072;
  const u16* Kh = Kb + bh * 131072;
  const u16* Vh = Vt + bh * 131072;

  // Q fragments for the whole kernel (A-operand layout: m=lanelo, k=quad*8+j)
  bvec8 aq[2][2];
#pragma unroll
  for (int i = 0; i < 2; ++i)
#pragma unroll
    for (int kk = 0; kk < 2; ++kk)
      aq[i][kk] = *(const bvec8*)&Qh[(sq0 + i * 16 + lanelo) * 64 + kk * 32 + quad * 8];

  fvec4 o[2][4] = {};
  float m_i[2][4], l_i[2][4];
#pragma unroll
  for (int i = 0; i < 2; ++i)
#pragma unroll
    for (int r = 0; r < 4; ++r) { m_i[i][r] = -3.0e38f; l_i[i][r] = 0.f; }

  // staging addresses (bank swizzle on global source)
  const u16* gK[4]; const u16* gV[4]; int ldof[4];
#pragma unroll
  for (int t = 0; t < 4; ++t) {
    int idx = (w * 4 + t) * 64 + lane;
    int rk = idx >> 3, bk = idx & 7;
    gK[t] = Kh + rk * 64 + ((bk ^ (rk & 7)) << 3);
    int rv = idx >> 4, bv = idx & 15;
    gV[t] = Vh + rv * 2048 + ((bv ^ (rv & 15)) << 3);
    ldof[t] = (w * 4 + t) * 512;
  }
  int koff[8][2], voff[4][4], poff[2][4];
#pragma unroll
  for (int j = 0; j < 8; ++j)
#pragma unroll
    for (int kk = 0; kk < 2; ++kk) {
      int rk = j * 16 + lanelo;
      koff[j][kk] = rk * 64 + (((kk * 4 + quad) ^ (rk & 7)) << 3);
    }
#pragma unroll
  for (int dj = 0; dj < 4; ++dj)
#pragma unroll
    for (int kq = 0; kq < 4; ++kq) {
      int rv = dj * 16 + lanelo;
      voff[dj][kq] = rv * 128 + (((kq * 4 + quad) ^ (rv & 15)) << 3);
    }
#pragma unroll
  for (int i = 0; i < 2; ++i)
#pragma unroll
    for (int kq = 0; kq < 4; ++kq) {
      int rp = i * 16 + lanelo;
      poff[i][kq] = rp * 128 + (((kq * 4 + quad) ^ (rp & 15)) << 3);
    }

  for (int sk0 = 0; sk0 < 2048; sk0 += 128) {
    __syncthreads();
#pragma unroll
    for (int t = 0; t < 4; ++t) {
      gl_lds16(gK[t] + sk0 * 64, &Ks[ldof[t]]);
      gl_lds16(gV[t] + sk0, &Vs[ldof[t]]);
    }
    __syncthreads();

    // scores: S[32 x 128] = Q' K^T  (scale already folded into Q)
    fvec4 sa[2][8] = {};
#pragma unroll
    for (int j = 0; j < 8; ++j) {
#pragma unroll
      for (int kk = 0; kk < 2; ++kk) {
        bvec8 bk = *(const bvec8*)&Ks[koff[j][kk]];
        sa[0][j] = __builtin_amdgcn_mfma_f32_16x16x32_bf16(aq[0][kk], bk, sa[0][j], 0, 0, 0);
        sa[1][j] = __builtin_amdgcn_mfma_f32_16x16x32_bf16(aq[1][kk], bk, sa[1][j], 0, 0, 0);
      }
    }

    // online softmax; write P (bf16) to per-wave LDS with block swizzle
#pragma unroll
    for (int i = 0; i < 2; ++i) {
#pragma unroll
      for (int r = 0; r < 4; ++r) {
        float mx = sa[i][0][r];
#pragma unroll
        for (int j = 1; j < 8; ++j) mx = fmaxf(mx, sa[i][j][r]);
#pragma unroll
        for (int msk = 1; msk < 16; msk <<= 1) mx = fmaxf(mx, __shfl_xor(mx, msk));
        const float mn = fmaxf(m_i[i][r], mx);
        const float al = __expf(m_i[i][r] - mn);
        m_i[i][r] = mn;
        float sum = 0.f;
        const int prow = i * 16 + quad * 4 + r;
        const int pbase = prow * 128;
        const int pxr = prow & 15;
#pragma unroll
        for (int j = 0; j < 8; ++j) {
          float p = __expf(sa[i][j][r] - mn);
          sum += p;
          int cb = j * 2 + (lanelo >> 3);
          Ps[w][pbase + ((cb ^ pxr) << 3) + (lanelo & 7)] = f2bf(p);
        }
#pragma unroll
        for (int msk = 1; msk < 16; msk <<= 1) sum += __shfl_xor(sum, msk);
        l_i[i][r] = l_i[i][r] * al + sum;
#pragma unroll
        for (int dj = 0; dj < 4; ++dj) o[i][dj][r] *= al;
      }
    }

    // O += P @ V   (P from LDS in A-layout, V^T tile is B-operand)
#pragma unroll
    for (int kq = 0; kq < 4; ++kq) {
      bvec8 ap0 = *(const bvec8*)&Ps[w][poff[0][kq]];
      bvec8 ap1 = *(const bvec8*)&Ps[w][poff[1][kq]];
#pragma unroll
      for (int dj = 0; dj < 4; ++dj) {
        bvec8 bv = *(const bvec8*)&Vs[voff[dj][kq]];
        o[0][dj] = __builtin_amdgcn_mfma_f32_16x16x32_bf16(ap0, bv, o[0][dj], 0, 0, 0);
        o[1][dj] = __builtin_amdgcn_mfma_f32_16x16x32_bf16(ap1, bv, o[1][dj], 0, 0, 0);
      }
    }
  }

  // epilogue: O/l -> Ob in [B,S,H*64] (= final-GEMM A layout), bf16
  const int b = bh >> 4, h = bh & 15;
#pragma unroll
  for (int i = 0; i < 2; ++i) {
#pragma unroll
    for (int r = 0; r < 4; ++r) {
      const float inv = 1.0f / l_i[i][r];
      const int sg = sq0 + i * 16 + quad * 4 + r;
#pragma unroll
      for (int dj = 0; dj < 4; ++dj)
        Ob[((b * 2048 + sg) * 16 + h) * 64 + dj * 16 + lanelo] = f2bf(o[i][dj][r] * inv);
    }
  }
}

// ---------------------------------------------------------------------------
extern "C" void kernel_launch(void* const* d_in, const int* in_sizes, int n_in,
                              void* d_out, int out_size, void* d_ws, size_t ws_size,
                              hipStream_t stream) {
  (void)in_sizes; (void)n_in; (void)out_size; (void)ws_size;
  const float* x  = (const float*)d_in[0];
  const float* wq = (const float*)d_in[1];
  const float* wk = (const float*)d_in[2];
  const float* wv = (const float*)d_in[3];
  const float* wf = (const float*)d_in[4];

  char* ws = (char*)d_ws;
  u16* xb  = (u16*)ws;                         // 16.78 MB; reused as Ob later
  u16* wqb = (u16*)(ws + 16777216);
  u16* wkb = (u16*)(ws + 18874368);
  u16* wvb = (u16*)(ws + 20971520);
  u16* wfb = (u16*)(ws + 23068672);
  u16* Qb  = (u16*)(ws + 25165824);            // [B,H,S,64] bf16, pre-scaled 1/8
  u16* Kb  = (u16*)(ws + 41943040);            // [B,H,S,64]
  u16* Vt  = (u16*)(ws + 58720256);            // [B,H,64,S]
  u16* Ob  = xb;                               // x dead after V projection

  cvt_bf16<<<8192, 256, 0, stream>>>(x, xb, 2097152);
  cvt_bf16<<<1024, 256, 0, stream>>>(wq, wqb, 262144);
  cvt_bf16<<<1024, 256, 0, stream>>>(wk, wkb, 262144);
  cvt_bf16<<<1024, 256, 0, stream>>>(wv, wvb, 262144);
  cvt_bf16<<<1024, 256, 0, stream>>>(wf, wfb, 262144);

  dim3 g(64, 8);
  gemm_bt<0><<<g, 256, 0, stream>>>(xb, wqb, Qb, 0.125f);   // Q, /sqrt(depth)
  gemm_bt<0><<<g, 256, 0, stream>>>(xb, wkb, Kb, 1.0f);     // K
  gemm_bt<2><<<g, 256, 0, stream>>>(xb, wvb, Vt, 1.0f);     // V transposed

  attn<<<dim3(16, 64), 256, 0, stream>>>(Qb, Kb, Vt, Ob);

  gemm_bt<3><<<g, 256, 0, stream>>>(Ob, wfb, d_out, 1.0f);  // final, fp32 out
}